// Round 8
// baseline (887.029 us; speedup 1.0000x reference)
//
#include <hip/hip_runtime.h>
#include <cstddef>

// ---------------- conv1 v3: (32,3,152,152) -> relu 11x11 -> (32,32,142,142)
__global__ __launch_bounds__(256, 2) void conv1_v3(const float* __restrict__ x,
                                                   const float* __restrict__ w,
                                                   const float* __restrict__ bias,
                                                   float* __restrict__ out) {
  __shared__ __align__(16) float wsp[33 * 32 * 12];
  __shared__ __align__(16) float xs[3][26][44];
  const int wt = blockIdx.x, ht = blockIdx.y, b = blockIdx.z;
  const int tid = threadIdx.x;
  const int posg = tid & 31;
  const int ocg = tid >> 5;
  const int owg = posg & 1;
  const int ohl = posg >> 1;
  const int ih0 = ht * 16, iw0 = wt * 32;

  for (int j = tid; j < 11616; j += 256) {
    const int kw = j % 11, oc = (j / 11) % 32, r = j / 352;
    wsp[(r * 32 + oc) * 12 + kw] = w[oc * 363 + r * 11 + kw];
  }
  for (int j = tid; j < 3 * 26 * 42; j += 256) {
    const int ic = j / 1092, r = (j % 1092) / 42, c = j % 42;
    const int ih = min(ih0 + r, 151), iw = min(iw0 + c, 151);
    xs[ic][r][c] = x[((size_t)b * 3 + ic) * 23104 + ih * 152 + iw];
  }
  __syncthreads();

  const int oh = ih0 + ohl;
  if (oh >= 142) return;
  float acc[4][16] = {};
  for (int ic = 0; ic < 3; ++ic) {
    for (int kh = 0; kh < 11; ++kh) {
      const int r = ic * 11 + kh;
      float xv[28];
      const float* xr = &xs[ic][ohl + kh][owg * 16];
      #pragma unroll
      for (int j = 0; j < 7; ++j) *(float4*)&xv[4 * j] = *(const float4*)&xr[4 * j];
      float wv[4][12];
      #pragma unroll
      for (int o = 0; o < 4; ++o) {
        const float* wr = &wsp[(r * 32 + ocg * 4 + o) * 12];
        *(float4*)&wv[o][0] = *(const float4*)&wr[0];
        *(float4*)&wv[o][4] = *(const float4*)&wr[4];
        *(float4*)&wv[o][8] = *(const float4*)&wr[8];
      }
      #pragma unroll
      for (int kw = 0; kw < 11; ++kw)
        #pragma unroll
        for (int o = 0; o < 4; ++o)
          #pragma unroll
          for (int p = 0; p < 16; ++p)
            acc[o][p] += xv[kw + p] * wv[o][kw];
    }
  }

  const int ow0 = iw0 + owg * 16;
  #pragma unroll
  for (int o = 0; o < 4; ++o) {
    const int oc = ocg * 4 + o;
    const float bv = bias[oc];
    float* op = &out[(((size_t)b * 32 + oc) * 142 + oh) * 142 + ow0];
    if (ow0 + 16 <= 142) {
      #pragma unroll
      for (int p = 0; p < 16; p += 2) {
        float2 rv;
        rv.x = fmaxf(acc[o][p] + bv, 0.f);
        rv.y = fmaxf(acc[o][p + 1] + bv, 0.f);
        *(float2*)&op[p] = rv;
      }
    } else {
      for (int p = 0; p < 16; ++p)
        if (ow0 + p < 142) op[p] = fmaxf(acc[o][p] + bv, 0.f);
    }
  }
}

// ---------------- maxpool 3x3 s2 p1
__global__ __launch_bounds__(256) void pool_3_2_1(const float* __restrict__ in,
                                                  float* __restrict__ out) {
  const int idx = blockIdx.x * 256 + threadIdx.x;
  const int total = 32 * 32 * 71 * 71;
  if (idx >= total) return;
  const int ow = idx % 71;
  const int oh = (idx / 71) % 71;
  const int bc = idx / (71 * 71);
  const float* base = in + (size_t)bc * 142 * 142;
  float m = -1e30f;
  #pragma unroll
  for (int kh = 0; kh < 3; ++kh) {
    const int ih = oh * 2 - 1 + kh;
    if (ih < 0 || ih >= 142) continue;
    #pragma unroll
    for (int kw = 0; kw < 3; ++kw) {
      const int iw = ow * 2 - 1 + kw;
      if (iw < 0 || iw >= 142) continue;
      m = fmaxf(m, base[ih * 142 + iw]);
    }
  }
  out[idx] = m;
}

// ---------------- conv2: ic-split x4 partials
__global__ __launch_bounds__(128, 2) void conv2_part(const float* __restrict__ x,
                                                     const float* __restrict__ w,
                                                     float* __restrict__ part) {
  __shared__ __align__(16) float wsp[2 * 9 * 16 * 12];
  __shared__ __align__(16) float xs[2][24][44];
  const int wt = blockIdx.x, ht = blockIdx.y;
  const int b = blockIdx.z >> 2, icg = blockIdx.z & 3;
  const int tid = threadIdx.x;
  const int posg = tid & 31;
  const int ocg = tid >> 5;
  const int owg = posg & 1, ohl = posg >> 1;
  const int ih0 = ht * 16, iw0 = wt * 32;
  float acc[4][16] = {};

  for (int ch = 0; ch < 4; ++ch) {
    __syncthreads();
    for (int j = tid; j < 2 * 9 * 16 * 9; j += 128) {
      const int kw = j % 9, oc = (j / 9) % 16, kh = (j / 144) % 9, icl = j / 1296;
      wsp[((icl * 9 + kh) * 16 + oc) * 12 + kw] =
          w[(size_t)oc * 2592 + (icg * 8 + ch * 2 + icl) * 81 + kh * 9 + kw];
    }
    for (int j = tid; j < 2 * 24 * 40; j += 128) {
      const int icl = j / 960, r = (j % 960) / 40, c = j % 40;
      const int ih = min(ih0 + r, 70), iw = min(iw0 + c, 70);
      xs[icl][r][c] =
          x[((size_t)b * 32 + icg * 8 + ch * 2 + icl) * 5041 + ih * 71 + iw];
    }
    __syncthreads();
    for (int icl = 0; icl < 2; ++icl) {
      for (int kh = 0; kh < 9; ++kh) {
        float xv[24];
        const float* xr = &xs[icl][ohl + kh][owg * 16];
        #pragma unroll
        for (int j = 0; j < 6; ++j) *(float4*)&xv[4 * j] = *(const float4*)&xr[4 * j];
        float wv[4][9];
        #pragma unroll
        for (int o = 0; o < 4; ++o) {
          const float* wr = &wsp[((icl * 9 + kh) * 16 + ocg * 4 + o) * 12];
          *(float4*)&wv[o][0] = *(const float4*)&wr[0];
          *(float4*)&wv[o][4] = *(const float4*)&wr[4];
          wv[o][8] = wr[8];
        }
        #pragma unroll
        for (int kw = 0; kw < 9; ++kw)
          #pragma unroll
          for (int o = 0; o < 4; ++o)
            #pragma unroll
            for (int p = 0; p < 16; ++p)
              acc[o][p] += xv[kw + p] * wv[o][kw];
      }
    }
  }

  const int oh = ih0 + ohl;
  if (oh >= 63) return;
  const int ow0 = iw0 + owg * 16;
  float* pp = part + (size_t)icg * 2032128;
  #pragma unroll
  for (int o = 0; o < 4; ++o) {
    const int oc = ocg * 4 + o;
    float* op = &pp[(((size_t)b * 16 + oc) * 63 + oh) * 63 + ow0];
    #pragma unroll
    for (int p = 0; p < 16; ++p)
      if (ow0 + p < 63) op[p] = acc[o][p];
  }
}

// ---------------- combineT: sum nicg partials + bias + relu, output TRANSPOSED
// part layout: [icg][b][16oc][npos]; outT layout: [oc][pos][b32].
// block = (oc, 64-pos tile); coalesced reads (over pos) and writes (over b).
__global__ __launch_bounds__(256) void combineT(const float* __restrict__ part,
                                                const float* __restrict__ bias,
                                                float* __restrict__ outT,
                                                int npos, int total, int nicg,
                                                int bias_pp) {
  __shared__ float tile[64][33];
  const int oc = blockIdx.x;
  const int pos0 = blockIdx.y * 64;
  const int tid = threadIdx.x;
  for (int j = tid; j < 2048; j += 256) {
    const int pl = j & 63;
    const int b = j >> 6;
    const int pos = min(pos0 + pl, npos - 1);
    const size_t idx = ((size_t)b * 16 + oc) * npos + pos;
    float v = 0.f;
    for (int g = 0; g < nicg; ++g) v += part[idx + (size_t)g * total];
    v += bias_pp ? bias[oc * npos + pos] : bias[oc];
    tile[pl][b] = fmaxf(v, 0.f);
  }
  __syncthreads();
  for (int j = tid; j < 2048; j += 256) {
    const int b = j & 31;
    const int pl = j >> 5;
    const int pos = pos0 + pl;
    if (pos < npos) outT[((size_t)oc * npos + pos) * 32 + b] = tile[pl][b];
  }
}

// ---------------- local conv v8: NO LDS. x pre-transposed to [ic][pos][b32] so
// x is read direct from global as aligned float4 (b-contiguous, L2/L3-hot).
// Wave = 4 pos x (2 og x 8 bg); thread = 8 oc x 4 b; ic-split x8 into partials.
// Weights streamed direct from global (8 float4 in flight per lane per kc).
template <int KH, int S, int IH, int OH>
__global__ __launch_bounds__(256, 4) void lc_v8(const float* __restrict__ xt,
                                                const float* __restrict__ w,
                                                float* __restrict__ part) {
  constexpr int KHW = KH * KH;
  constexpr int NPOS = OH * OH;
  constexpr int WOC = 16 * KHW;
  constexpr int KC4 = KHW / 4;               // 20 / 12 / 6
  const int tid = threadIdx.x;
  const int lane = tid & 63, wvi = tid >> 6;
  const int p = lane >> 4;                   // 0..3 position within wave
  const int og = (lane >> 3) & 1;            // oc0 = og*8
  const int bg = lane & 7;                   // b0 = bg*4
  int mypos = blockIdx.x * 16 + wvi * 4 + p;
  if (mypos >= NPOS) mypos = NPOS - 1;       // dup positions write same value
  const int icg = blockIdx.y;                // 0..7 (2 ic each)
  const int oh = mypos / OH, ow = mypos % OH;

  float acc[8][4] = {};
  #pragma unroll 1
  for (int ics = 0; ics < 2; ++ics) {
    const int ic = icg * 2 + ics;
    const float* wic = w + ((size_t)mypos * 16 + og * 8) * WOC + (size_t)ic * KHW;
    const float* xic =
        xt + (((size_t)ic * IH + oh * S) * IH + ow * S) * 32 + bg * 4;
    #pragma unroll 1
    for (int kc = 0; kc < KC4; ++kc) {
      float4 wf[8];
      #pragma unroll
      for (int o = 0; o < 8; ++o)
        wf[o] = *(const float4*)&wic[o * WOC + kc * 4];
      float4 xv[4];
      #pragma unroll
      for (int kk = 0; kk < 4; ++kk) {
        const int k = kc * 4 + kk;
        const int kh = k / KH, kw = k - kh * KH;
        xv[kk] = *(const float4*)&xic[(kh * IH + kw) * 32];
      }
      #pragma unroll
      for (int kk = 0; kk < 4; ++kk) {
        const float4 xk = xv[kk];
        #pragma unroll
        for (int o = 0; o < 8; ++o) {
          const float wv = (kk == 0) ? wf[o].x
                         : (kk == 1) ? wf[o].y
                         : (kk == 2) ? wf[o].z
                                     : wf[o].w;
          acc[o][0] += wv * xk.x;
          acc[o][1] += wv * xk.y;
          acc[o][2] += wv * xk.z;
          acc[o][3] += wv * xk.w;
        }
      }
    }
    {  // tail k = KHW-1 (KHW % 4 == 1 for 81/49/25)
      const int k = KHW - 1;
      const float4 xk = *(const float4*)&xic[((KH - 1) * IH + (KH - 1)) * 32];
      #pragma unroll
      for (int o = 0; o < 8; ++o) {
        const float wv = wic[o * WOC + k];
        acc[o][0] += wv * xk.x;
        acc[o][1] += wv * xk.y;
        acc[o][2] += wv * xk.z;
        acc[o][3] += wv * xk.w;
      }
    }
  }

  float* pp = part + (size_t)icg * (32 * 16 * NPOS);
  #pragma unroll
  for (int o = 0; o < 8; ++o) {
    const int oc = og * 8 + o;
    #pragma unroll
    for (int i = 0; i < 4; ++i) {
      const int b = bg * 4 + i;
      pp[(((size_t)b * 16 + oc) * OH + oh) * OH + ow] = acc[o][i];
    }
  }
}

// ---------------- fc1: reg-tiled GEMM; xt = h5T ([oc][pos][b] == [k][b])
__global__ __launch_bounds__(256) void fc1_v2(const float* __restrict__ xt,
                                              const float* __restrict__ w,
                                              const float* __restrict__ bias,
                                              float* __restrict__ out) {
  const int lane = threadIdx.x & 63;
  const int b0 = (threadIdx.x >> 6) * 8;
  const int n0 = blockIdx.x * 8;
  float acc[8][8] = {};
  for (int it = 0; it < 28; ++it) {
    const int kb = it * 256 + lane * 4;
    float4 wf[8], xa[4], xb[4];
    if (kb < 7056) {
      #pragma unroll
      for (int n = 0; n < 8; ++n)
        wf[n] = *(const float4*)&w[(size_t)(n0 + n) * 7056 + kb];
      #pragma unroll
      for (int j = 0; j < 4; ++j) {
        xa[j] = *(const float4*)&xt[(size_t)(kb + j) * 32 + b0];
        xb[j] = *(const float4*)&xt[(size_t)(kb + j) * 32 + b0 + 4];
      }
    } else {
      #pragma unroll
      for (int n = 0; n < 8; ++n) wf[n] = make_float4(0.f, 0.f, 0.f, 0.f);
      #pragma unroll
      for (int j = 0; j < 4; ++j) {
        xa[j] = make_float4(0.f, 0.f, 0.f, 0.f);
        xb[j] = make_float4(0.f, 0.f, 0.f, 0.f);
      }
    }
    #pragma unroll
    for (int n = 0; n < 8; ++n) {
      const float wk[4] = {wf[n].x, wf[n].y, wf[n].z, wf[n].w};
      #pragma unroll
      for (int j = 0; j < 4; ++j) {
        acc[n][0] += wk[j] * xa[j].x;
        acc[n][1] += wk[j] * xa[j].y;
        acc[n][2] += wk[j] * xa[j].z;
        acc[n][3] += wk[j] * xa[j].w;
        acc[n][4] += wk[j] * xb[j].x;
        acc[n][5] += wk[j] * xb[j].y;
        acc[n][6] += wk[j] * xb[j].z;
        acc[n][7] += wk[j] * xb[j].w;
      }
    }
  }
  #pragma unroll
  for (int n = 0; n < 8; ++n)
    #pragma unroll
    for (int c = 0; c < 8; ++c)
      #pragma unroll
      for (int m = 1; m < 64; m <<= 1)
        acc[n][c] += __shfl_xor(acc[n][c], m, 64);
  float val = 0.f;
  #pragma unroll
  for (int n = 0; n < 8; ++n)
    #pragma unroll
    for (int c = 0; c < 8; ++c)
      if (lane == n * 8 + c) val = acc[n][c];
  const int n_l = lane >> 3, b_l = lane & 7;
  out[(size_t)(b0 + b_l) * 4096 + n0 + n_l] = val + bias[n0 + n_l];
}

extern "C" void kernel_launch(void* const* d_in, const int* in_sizes, int n_in,
                              void* d_out, int out_size, void* d_ws, size_t ws_size,
                              hipStream_t stream) {
  const float* x       = (const float*)d_in[0];
  const float* conv1_w = (const float*)d_in[1];
  const float* conv1_b = (const float*)d_in[2];
  const float* conv2_w = (const float*)d_in[3];
  const float* conv2_b = (const float*)d_in[4];
  const float* lc1_w   = (const float*)d_in[5];
  const float* lc1_b   = (const float*)d_in[6];
  const float* lc2_w   = (const float*)d_in[7];
  const float* lc2_b   = (const float*)d_in[8];
  const float* lc3_w   = (const float*)d_in[9];
  const float* lc3_b   = (const float*)d_in[10];
  const float* fc1_w   = (const float*)d_in[11];
  const float* fc1_b   = (const float*)d_in[12];
  float* out = (float*)d_out;
  char* ws = (char*)d_ws;

  // layout (bytes):
  float* h1  = (float*)(ws + 0);           // 32*32*142*142      82,591,744 (dead after pool)
  float* p1  = (float*)(ws + 82591744);    // 32*32*71*71        20,647,936 (dead after conv2_part)
  float* h2T = (float*)(ws + 103239680);   // 16*3969*32          8,128,512
  float* h3T = (float*)(ws + 0);           // 16*3025*32          6,195,200
  float* h4T = (float*)(ws + 8388608);     // 16*625*32           1,280,000
  float* h5T = (float*)(ws + 16777216);    // 16*441*32             903,168
  float* c2p = (float*)(ws + 41943040);    // 4*32*16*3969       32,514,048 (dead after its combineT)
  float* lcp = (float*)(ws + 41943040);    // 8*32*16*3025 max   49,561,600 (reused per lc layer)

  conv1_v3<<<dim3(5, 9, 32), 256, 0, stream>>>(x, conv1_w, conv1_b, h1);
  pool_3_2_1<<<20164, 256, 0, stream>>>(h1, p1);
  conv2_part<<<dim3(2, 4, 128), 128, 0, stream>>>(p1, conv2_w, c2p);
  combineT<<<dim3(16, 63), 256, 0, stream>>>(c2p, conv2_b, h2T, 3969, 2032128, 4, 0);

  lc_v8<9, 1, 63, 55><<<dim3(190, 8), 256, 0, stream>>>(h2T, lc1_w, lcp);
  combineT<<<dim3(16, 48), 256, 0, stream>>>(lcp, lc1_b, h3T, 3025, 1548800, 8, 1);
  lc_v8<7, 2, 55, 25><<<dim3(40, 8), 256, 0, stream>>>(h3T, lc2_w, lcp);
  combineT<<<dim3(16, 10), 256, 0, stream>>>(lcp, lc2_b, h4T, 625, 320000, 8, 1);
  lc_v8<5, 1, 25, 21><<<dim3(28, 8), 256, 0, stream>>>(h4T, lc3_w, lcp);
  combineT<<<dim3(16, 7), 256, 0, stream>>>(lcp, lc3_b, h5T, 441, 225792, 8, 1);

  fc1_v2<<<512, 256, 0, stream>>>(h5T, fc1_w, fc1_b, out);
}